// Round 1
// baseline (396.873 us; speedup 1.0000x reference)
//
#include <hip/hip_runtime.h>
#include <hip/hip_bf16.h>
#include <cstdint>

#define N_NODES 8192
#define F_IN    256
#define F_OUT   64
#define ALPHA   0.2f

// ---------------------------------------------------------------------------
// Kernel 1: fts = x @ W   (fp32, M=8192 K=256 N=64)
// Block = 256 threads, 32 rows/block. W staged in LDS (64 KB). x read from
// global: each row pair is read by 16 threads at identical addresses ->
// broadcast-coalesced, sequential 16B chunks -> L1-friendly, read-once 8 MB.
// ---------------------------------------------------------------------------
__global__ __launch_bounds__(256) void k_proj(const float* __restrict__ x,
                                              const float* __restrict__ W,
                                              float* __restrict__ fts) {
    __shared__ __align__(16) float ws[F_IN][F_OUT];   // 64 KB exactly
    const int t = threadIdx.x;
    const int row0 = blockIdx.x * 32;

    {   // stage W: 4096 float4, 16 per thread, linear copy
        const float4* W4 = (const float4*)W;
        float4* S4 = (float4*)&ws[0][0];
        #pragma unroll
        for (int i = 0; i < 16; ++i) S4[i * 256 + t] = W4[i * 256 + t];
    }
    __syncthreads();

    const int rg = t >> 4;          // 0..15  (quarter-wave shares rg -> x broadcast)
    const int cg = t & 15;          // 0..15
    const int r0 = row0 + rg * 2;
    const int c0 = cg * 4;

    float4 acc0 = {0.f,0.f,0.f,0.f}, acc1 = {0.f,0.f,0.f,0.f};
    const float4* xr0 = (const float4*)(x + (size_t)r0 * F_IN);
    const float4* xr1 = (const float4*)(x + (size_t)(r0 + 1) * F_IN);

    #pragma unroll 4
    for (int kq = 0; kq < 64; ++kq) {
        const float4 xa = xr0[kq];
        const float4 xb = xr1[kq];
        const float4 w0 = *(const float4*)&ws[kq*4+0][c0];
        const float4 w1 = *(const float4*)&ws[kq*4+1][c0];
        const float4 w2 = *(const float4*)&ws[kq*4+2][c0];
        const float4 w3 = *(const float4*)&ws[kq*4+3][c0];
        acc0.x += xa.x*w0.x + xa.y*w1.x + xa.z*w2.x + xa.w*w3.x;
        acc0.y += xa.x*w0.y + xa.y*w1.y + xa.z*w2.y + xa.w*w3.y;
        acc0.z += xa.x*w0.z + xa.y*w1.z + xa.z*w2.z + xa.w*w3.z;
        acc0.w += xa.x*w0.w + xa.y*w1.w + xa.z*w2.w + xa.w*w3.w;
        acc1.x += xb.x*w0.x + xb.y*w1.x + xb.z*w2.x + xb.w*w3.x;
        acc1.y += xb.x*w0.y + xb.y*w1.y + xb.z*w2.y + xb.w*w3.y;
        acc1.z += xb.x*w0.z + xb.y*w1.z + xb.z*w2.z + xb.w*w3.z;
        acc1.w += xb.x*w0.w + xb.y*w1.w + xb.z*w2.w + xb.w*w3.w;
    }
    float* o = fts + (size_t)r0 * F_OUT + c0;
    *(float4*)o          = acc0;
    *(float4*)(o + F_OUT) = acc1;
}

// ---------------------------------------------------------------------------
// Kernel 2: f1[i] = fts[i,:].a1 + b1 ; f2[i] = fts[i,:].a2 + b2
// One thread per row (8192 threads). Tiny; fts mostly L2-resident.
// ---------------------------------------------------------------------------
__global__ __launch_bounds__(256) void k_f12(const float* __restrict__ fts,
                                             const float* __restrict__ a1,
                                             const float* __restrict__ b1,
                                             const float* __restrict__ a2,
                                             const float* __restrict__ b2,
                                             float* __restrict__ f1,
                                             float* __restrict__ f2) {
    const int row = blockIdx.x * blockDim.x + threadIdx.x;
    const float4* v4 = (const float4*)(fts + (size_t)row * F_OUT);
    const float4* A1 = (const float4*)a1;
    const float4* A2 = (const float4*)a2;
    float s1 = 0.f, s2 = 0.f;
    #pragma unroll
    for (int q = 0; q < 16; ++q) {
        const float4 v = v4[q], u1 = A1[q], u2 = A2[q];
        s1 += v.x*u1.x + v.y*u1.y + v.z*u1.z + v.w*u1.w;
        s2 += v.x*u2.x + v.y*u2.y + v.z*u2.z + v.w*u2.w;
    }
    f1[row] = s1 + b1[0];
    f2[row] = s2 + b2[0];
}

// ---------------------------------------------------------------------------
// Kernel 3: per-row fused  score -> softmax -> sparse PV -> bias -> ELU
// One block (256 thr = 4 waves) per row. adj row streamed once (32 KB).
// p==0 entries (masked, exp underflow) contribute exactly 0 -> skipped via
// wave ballot; identical numerics to the dense reference sum.
// ---------------------------------------------------------------------------
__global__ __launch_bounds__(256) void k_attn(const float* __restrict__ adj,
                                              const float* __restrict__ fts,
                                              const float* __restrict__ f1,
                                              const float* __restrict__ f2,
                                              const float* __restrict__ bias,
                                              float* __restrict__ out) {
    __shared__ __align__(16) float p_lds[N_NODES];   // 32 KB
    __shared__ float red_max[4], red_sum[4];
    __shared__ float opart[4][F_OUT];

    const int row  = blockIdx.x;
    const int t    = threadIdx.x;
    const int lane = t & 63;
    const int w    = t >> 6;

    const float4* arow = (const float4*)(adj + (size_t)row * N_NODES);
    const float4* f24  = (const float4*)f2;
    const float   f1r  = f1[row];

    // ---- phase 1: scores into registers, local max ----
    float s[32];
    float m = -3.0e38f;
    #pragma unroll
    for (int c = 0; c < 8; ++c) {
        const int q = c * 256 + t;               // float4 index, coalesced
        const float4 a  = arow[q];
        const float4 fv = f24[q];
        float4 sv;
        { const float l = f1r + fv.x; sv.x = fmaxf(l, ALPHA * l) + a.x; }
        { const float l = f1r + fv.y; sv.y = fmaxf(l, ALPHA * l) + a.y; }
        { const float l = f1r + fv.z; sv.z = fmaxf(l, ALPHA * l) + a.z; }
        { const float l = f1r + fv.w; sv.w = fmaxf(l, ALPHA * l) + a.w; }
        s[4*c+0] = sv.x; s[4*c+1] = sv.y; s[4*c+2] = sv.z; s[4*c+3] = sv.w;
        m = fmaxf(m, fmaxf(fmaxf(sv.x, sv.y), fmaxf(sv.z, sv.w)));
    }
    #pragma unroll
    for (int off = 32; off >= 1; off >>= 1)
        m = fmaxf(m, __shfl_xor(m, off, 64));
    if (lane == 0) red_max[w] = m;
    __syncthreads();
    m = fmaxf(fmaxf(red_max[0], red_max[1]), fmaxf(red_max[2], red_max[3]));

    // ---- phase 2: p = exp(s - m) into LDS, local sum ----
    float lsum = 0.f;
    #pragma unroll
    for (int c = 0; c < 8; ++c) {
        const int q = c * 256 + t;
        float4 pv;
        pv.x = __expf(s[4*c+0] - m);
        pv.y = __expf(s[4*c+1] - m);
        pv.z = __expf(s[4*c+2] - m);
        pv.w = __expf(s[4*c+3] - m);
        lsum += pv.x + pv.y + pv.z + pv.w;
        ((float4*)p_lds)[q] = pv;
    }
    #pragma unroll
    for (int off = 32; off >= 1; off >>= 1)
        lsum += __shfl_xor(lsum, off, 64);
    if (lane == 0) red_sum[w] = lsum;
    __syncthreads();
    const float sum = red_sum[0] + red_sum[1] + red_sum[2] + red_sum[3];

    // ---- phase 3: sparse PV. lane = output column; wave w owns 2048 j's ----
    float acc = 0.f;
    const int jbase0 = w * 2048;
    for (int it = 0; it < 32; ++it) {
        const int jb = jbase0 + it * 64;
        const float p = p_lds[jb + lane];        // stride-1: conflict-free
        unsigned long long mk = __ballot(p > 0.f);
        while (mk) {
            const int b = __ffsll(mk) - 1;
            mk &= mk - 1;
            const float pb = __shfl(p, b, 64);
            acc += pb * fts[(size_t)(jb + b) * F_OUT + lane];  // coalesced 256B, L2-hit
        }
    }
    opart[w][lane] = acc;
    __syncthreads();

    if (w == 0) {
        const float tot = opart[0][lane] + opart[1][lane] + opart[2][lane] + opart[3][lane];
        const float v = tot / sum + bias[lane];
        out[(size_t)row * F_OUT + lane] = (v > 0.f) ? v : expm1f(v);
    }
}

// ---------------------------------------------------------------------------
extern "C" void kernel_launch(void* const* d_in, const int* in_sizes, int n_in,
                              void* d_out, int out_size, void* d_ws, size_t ws_size,
                              hipStream_t stream) {
    const float* x    = (const float*)d_in[0];
    const float* adj  = (const float*)d_in[1];
    const float* W    = (const float*)d_in[2];
    const float* a1   = (const float*)d_in[3];
    const float* b1   = (const float*)d_in[4];
    const float* a2   = (const float*)d_in[5];
    const float* b2   = (const float*)d_in[6];
    const float* bias = (const float*)d_in[7];
    float* out = (float*)d_out;

    float* fts = (float*)d_ws;                       // 8192*64 fp32 = 2 MB
    float* f1  = fts + (size_t)N_NODES * F_OUT;      // 32 KB
    float* f2  = f1 + N_NODES;                       // 32 KB

    k_proj<<<N_NODES / 32, 256, 0, stream>>>(x, W, fts);
    k_f12 <<<N_NODES / 256, 256, 0, stream>>>(fts, a1, b1, a2, b2, f1, f2);
    k_attn<<<N_NODES, 256, 0, stream>>>(adj, fts, f1, f2, bias, out);
}